// Round 6
// baseline (760.356 us; speedup 1.0000x reference)
//
#include <hip/hip_runtime.h>
#include <hip/hip_bf16.h>

#define B_ 32
#define S_ 256
#define E_ 768
#define H_ 32
#define D_ 24
#define NTOT 1664   // 768 (q) + 768 (k) + 96 (vw) + 32 pad
#define LK 40       // gemm LDS row stride (bf16) for 32-wide K tiles

typedef __hip_bfloat16 bf16;
typedef __attribute__((ext_vector_type(8))) short short8;
typedef __attribute__((ext_vector_type(4))) float floatx4;

// ---------------------------------------------------------------------------
// feats fp32 -> bf16, 4 elems/thread
// ---------------------------------------------------------------------------
__global__ __launch_bounds__(256) void cast_feats(
    const float* __restrict__ in, bf16* __restrict__ outp, int n4)
{
  int i = blockIdx.x * 256 + threadIdx.x;
  if (i < n4) {
    float4 v = reinterpret_cast<const float4*>(in)[i];
    union { ushort4 u; bf16 b[4]; } pk;
    pk.b[0] = (bf16)v.x; pk.b[1] = (bf16)v.y;
    pk.b[2] = (bf16)v.z; pk.b[3] = (bf16)v.w;
    reinterpret_cast<ushort4*>(outp)[i] = pk.u;
  }
}

// ---------------------------------------------------------------------------
// Coalesced transpose Wq/Wk (fp32 [k][n]) -> Wt rows [n][k] (bf16), qscale
// folded into the q half. 64x64 tiles via LDS (stride 65: 2-way max).
// ---------------------------------------------------------------------------
__global__ __launch_bounds__(256) void transpose_w(
    const float* __restrict__ Wq, const float* __restrict__ Wk,
    bf16* __restrict__ Wt)
{
  __shared__ float tile[64][65];
  int z = blockIdx.z;
  const float* src = z ? Wk : Wq;
  float scale = z ? 1.0f : 0.20412414523193154f;  // 24^-0.5
  int k0 = blockIdx.x * 64, n0 = blockIdx.y * 64;
  int tid = threadIdx.x;
  int rr = tid >> 4, cc = (tid & 15) * 4;
  #pragma unroll
  for (int i = 0; i < 4; i++) {
    float4 v = *reinterpret_cast<const float4*>(
        &src[(size_t)(k0 + rr + i * 16) * E_ + n0 + cc]);
    tile[rr + i * 16][cc + 0] = v.x;
    tile[rr + i * 16][cc + 1] = v.y;
    tile[rr + i * 16][cc + 2] = v.z;
    tile[rr + i * 16][cc + 3] = v.w;
  }
  __syncthreads();
  #pragma unroll
  for (int i = 0; i < 4; i++) {
    int n = rr + i * 16;
    union { ushort4 u; bf16 h[4]; } pk;
    #pragma unroll
    for (int j = 0; j < 4; j++) pk.h[j] = (bf16)(tile[cc + j][n] * scale);
    *reinterpret_cast<ushort4*>(
        &Wt[(size_t)(z * 768 + n0 + n) * E_ + k0 + cc]) = pk.u;
  }
}

// ---------------------------------------------------------------------------
// Wvx rows of Wt (1536..1631): Wt[1536+nn][k] = sum_c Wv[k][h*24+c]*Wf_x[...]
// (adjacent threads share k -> L1 broadcast). Plus fused bias biasf[NTOT].
// ---------------------------------------------------------------------------
__global__ __launch_bounds__(256) void prep_vwx(
    const float* __restrict__ Wv, const float* __restrict__ bv,
    const float* __restrict__ bq, const float* __restrict__ bk,
    const float* __restrict__ Wfx, const float* __restrict__ Wfy,
    const float* __restrict__ Wfz,
    bf16* __restrict__ Wt, float* __restrict__ biasf)
{
  const float qscale = 0.20412414523193154f;
  int gid = blockIdx.x * 256 + threadIdx.x;
  if (gid < 96 * E_) {
    int k = gid / 96, nn = gid % 96;
    int x = nn >> 5, h = nn & 31;
    const float* Wf = (x == 0) ? Wfx : (x == 1 ? Wfy : Wfz);
    float s = 0.f;
    #pragma unroll
    for (int c = 0; c < D_; c++)
      s += Wv[(size_t)k * E_ + h * D_ + c] * Wf[h * D_ + c];
    Wt[(size_t)(1536 + nn) * E_ + k] = (bf16)s;
  } else {
    int n = gid - 96 * E_;
    if (n < NTOT) {
      float val;
      if (n < 768) {
        val = bq[n] * qscale;
      } else if (n < 1536) {
        val = bk[n - 768];
      } else if (n < 1632) {
        int nn = n - 1536, x = nn >> 5, h = nn & 31;
        const float* Wf = (x == 0) ? Wfx : (x == 1 ? Wfy : Wfz);
        float s = 0.f;
        #pragma unroll
        for (int c = 0; c < D_; c++)
          s += bv[h * D_ + c] * Wf[h * D_ + c];
        val = s;
      } else {
        val = 0.f;
      }
      biasf[n] = val;
    }
  }
}

// ---------------------------------------------------------------------------
// MFMA GEMM: C[8192][1664] = A@Wt^T + biasf; split epilogue q/k/vw.
// 128x128 tile, BK=32, 4 waves, 4x4 16x16x32 frags, 1-stage reg prefetch.
// ---------------------------------------------------------------------------
__global__ __launch_bounds__(256) void gemm_qkv(
    const bf16* __restrict__ A, const bf16* __restrict__ Wt,
    const float* __restrict__ biasf,
    bf16* __restrict__ qout, bf16* __restrict__ kout,
    float* __restrict__ vwout)
{
  __shared__ __align__(16) short As[128 * LK];
  __shared__ __align__(16) short Bs[128 * LK];
  int tid = threadIdx.x;
  int m0 = blockIdx.y * 128, n0 = blockIdx.x * 128;
  int lrow = tid >> 2, lcol = (tid & 3) * 8;
  int wave = tid >> 6, lane = tid & 63;
  int wm = (wave >> 1) * 64, wn = (wave & 1) * 64;
  int fr = lane & 15, quad = lane >> 4;

  floatx4 acc[4][4];
  const floatx4 zero = {0.f, 0.f, 0.f, 0.f};
  #pragma unroll
  for (int i = 0; i < 4; i++)
    #pragma unroll
    for (int j = 0; j < 4; j++) acc[i][j] = zero;

  const bf16* Aptr = A + (size_t)(m0 + lrow) * E_ + lcol;
  const bf16* Bptr = Wt + (size_t)(n0 + lrow) * E_ + lcol;
  float4 av0 = *reinterpret_cast<const float4*>(Aptr);
  float4 av1 = *reinterpret_cast<const float4*>(Aptr + (size_t)64 * E_);
  float4 bv0 = *reinterpret_cast<const float4*>(Bptr);
  float4 bv1 = *reinterpret_cast<const float4*>(Bptr + (size_t)64 * E_);

  for (int k0 = 0; k0 < E_; k0 += 32) {
    __syncthreads();
    *reinterpret_cast<float4*>(&As[lrow * LK + lcol]) = av0;
    *reinterpret_cast<float4*>(&As[(lrow + 64) * LK + lcol]) = av1;
    *reinterpret_cast<float4*>(&Bs[lrow * LK + lcol]) = bv0;
    *reinterpret_cast<float4*>(&Bs[(lrow + 64) * LK + lcol]) = bv1;
    __syncthreads();
    if (k0 + 32 < E_) {
      av0 = *reinterpret_cast<const float4*>(Aptr + k0 + 32);
      av1 = *reinterpret_cast<const float4*>(Aptr + (size_t)64 * E_ + k0 + 32);
      bv0 = *reinterpret_cast<const float4*>(Bptr + k0 + 32);
      bv1 = *reinterpret_cast<const float4*>(Bptr + (size_t)64 * E_ + k0 + 32);
    }
    short8 af[4], bfr[4];
    #pragma unroll
    for (int t = 0; t < 4; t++)
      af[t] = *reinterpret_cast<const short8*>(
          &As[(wm + t * 16 + fr) * LK + quad * 8]);
    #pragma unroll
    for (int t = 0; t < 4; t++)
      bfr[t] = *reinterpret_cast<const short8*>(
          &Bs[(wn + t * 16 + fr) * LK + quad * 8]);
    #pragma unroll
    for (int ti = 0; ti < 4; ti++)
      #pragma unroll
      for (int tj = 0; tj < 4; tj++)
        acc[ti][tj] = __builtin_amdgcn_mfma_f32_16x16x32_bf16(
            af[ti], bfr[tj], acc[ti][tj], 0, 0, 0);
  }

  #pragma unroll
  for (int ti = 0; ti < 4; ti++) {
    #pragma unroll
    for (int tj = 0; tj < 4; tj++) {
      int n = n0 + wn + tj * 16 + fr;
      float bias = biasf[n];
      #pragma unroll
      for (int r = 0; r < 4; r++) {
        int m = m0 + wm + ti * 16 + quad * 4 + r;
        int b = m >> 8, s = m & 255;
        float val = acc[ti][tj][r] + bias;
        if (n < 768) {
          int h = n / 24, d = n - h * 24;
          qout[(((size_t)b * H_ + h) * S_ + s) * D_ + d] = (bf16)val;
        } else if (n < 1536) {
          int n2 = n - 768;
          int h = n2 / 24, d = n2 - h * 24;
          kout[(((size_t)b * H_ + h) * S_ + s) * D_ + d] = (bf16)val;
        } else if (n < 1632) {
          int nn = n - 1536, x = nn >> 5, h = nn & 31;
          vwout[(((size_t)x * B_ + b) * H_ + h) * S_ + s] = val;
        }
      }
    }
  }
}

// ---------------------------------------------------------------------------
// Attention v3 (MFMA): block = (b,h). q,k staged in LDS as bf16 [256][32]
// (K padded 24->32 with zeros), vw f32. Each wave: 4 s-tiles of 16 rows;
// per s-tile 16 one-shot 16x16x32 MFMAs give scores; exp (no max-sub:
// scores ~N(0,2), fp32-safe) + bias; accumulate l/ax/ay/az in regs across
// t-tiles; ONE 4-level 16-lane reduction per s-tile; atomicAdd 3 floats/row.
// ---------------------------------------------------------------------------
__global__ __launch_bounds__(256, 4) void attn_kernel(
    const bf16* __restrict__ qg, const bf16* __restrict__ kg,
    const float* __restrict__ vwg, const float* __restrict__ biasg,
    const float* __restrict__ dpg, float* __restrict__ out)
{
  __shared__ __align__(16) short qs[S_ * 32];
  __shared__ __align__(16) short ks[S_ * 32];
  __shared__ float vwl[3 * S_];
  int bh = blockIdx.x;
  int b = bh >> 5, h = bh & 31;
  int tid = threadIdx.x;

  // stage: thread t copies q/k row t (48B) + zero-pad to 64B
  {
    const float4* qrow = reinterpret_cast<const float4*>(
        qg + ((size_t)bh * S_ + tid) * D_);
    const float4* krow = reinterpret_cast<const float4*>(
        kg + ((size_t)bh * S_ + tid) * D_);
    float4 zz = {0.f, 0.f, 0.f, 0.f};
    *reinterpret_cast<float4*>(&qs[tid * 32 + 0])  = qrow[0];
    *reinterpret_cast<float4*>(&qs[tid * 32 + 8])  = qrow[1];
    *reinterpret_cast<float4*>(&qs[tid * 32 + 16]) = qrow[2];
    *reinterpret_cast<float4*>(&qs[tid * 32 + 24]) = zz;
    *reinterpret_cast<float4*>(&ks[tid * 32 + 0])  = krow[0];
    *reinterpret_cast<float4*>(&ks[tid * 32 + 8])  = krow[1];
    *reinterpret_cast<float4*>(&ks[tid * 32 + 16]) = krow[2];
    *reinterpret_cast<float4*>(&ks[tid * 32 + 24]) = zz;
    #pragma unroll
    for (int x = 0; x < 3; x++)
      vwl[x * S_ + tid] = vwg[(((size_t)x * B_ + b) * H_ + h) * S_ + tid];
  }
  __syncthreads();

  int wave = tid >> 6, lane = tid & 63;
  int fr = lane & 15, quad = lane >> 4;
  const float* biasbh = biasg + (size_t)bh * S_ * S_;
  const floatx4 zero = {0.f, 0.f, 0.f, 0.f};

  for (int it = 0; it < 4; it++) {
    int s0 = it * 64 + wave * 16;
    short8 afrag = *reinterpret_cast<const short8*>(
        &qs[(s0 + fr) * 32 + quad * 8]);
    float l[4] = {0.f, 0.f, 0.f, 0.f};
    float ax[4] = {0.f, 0.f, 0.f, 0.f};
    float ay[4] = {0.f, 0.f, 0.f, 0.f};
    float az[4] = {0.f, 0.f, 0.f, 0.f};

    #pragma unroll
    for (int tt = 0; tt < 16; tt++) {
      short8 bfrag = *reinterpret_cast<const short8*>(
          &ks[(tt * 16 + fr) * 32 + quad * 8]);
      floatx4 c = __builtin_amdgcn_mfma_f32_16x16x32_bf16(
          afrag, bfrag, zero, 0, 0, 0);
      int t = tt * 16 + fr;
      float vx = vwl[t], vy = vwl[S_ + t], vz = vwl[2 * S_ + t];
      #pragma unroll
      for (int r = 0; r < 4; r++) {
        int s = s0 + quad * 4 + r;
        float e = __expf(c[r] + biasbh[(size_t)s * S_ + t]);
        const float* dp = dpg + ((size_t)(b * S_ + s) * S_ + t) * 3;
        l[r] += e;
        ax[r] += e * dp[0] * vx;
        ay[r] += e * dp[1] * vy;
        az[r] += e * dp[2] * vz;
      }
    }

    #pragma unroll
    for (int o = 1; o < 16; o <<= 1) {
      #pragma unroll
      for (int r = 0; r < 4; r++) {
        l[r]  += __shfl_xor(l[r], o);
        ax[r] += __shfl_xor(ax[r], o);
        ay[r] += __shfl_xor(ay[r], o);
        az[r] += __shfl_xor(az[r], o);
      }
    }
    if (fr == 0) {
      #pragma unroll
      for (int r = 0; r < 4; r++) {
        int s = s0 + quad * 4 + r;
        float inv = 1.0f / l[r];
        float* op = out + (size_t)(b * S_ + s) * 3;
        atomicAdd(op + 0, ax[r] * inv);
        atomicAdd(op + 1, ay[r] * inv);
        atomicAdd(op + 2, az[r] * inv);
      }
    }
  }
}

// ---------------------------------------------------------------------------
extern "C" void kernel_launch(void* const* d_in, const int* in_sizes, int n_in,
                              void* d_out, int out_size, void* d_ws, size_t ws_size,
                              hipStream_t stream)
{
  const float* feats     = (const float*)d_in[0];
  const float* attn_bias = (const float*)d_in[1];
  const float* delta_pos = (const float*)d_in[2];
  const float* Wq        = (const float*)d_in[3];
  const float* bq        = (const float*)d_in[4];
  const float* Wk        = (const float*)d_in[5];
  const float* bk        = (const float*)d_in[6];
  const float* Wv        = (const float*)d_in[7];
  const float* bv        = (const float*)d_in[8];
  const float* Wfx       = (const float*)d_in[9];
  const float* Wfy       = (const float*)d_in[10];
  const float* Wfz       = (const float*)d_in[11];

  char* ws = (char*)d_ws;
  size_t off = 0;
  auto alloc = [&](size_t bytes) -> void* {
    void* p = ws + off;
    off = (off + bytes + 255) & ~(size_t)255;
    return p;
  };
  bf16*  ws_fb   = (bf16*) alloc((size_t)B_ * S_ * E_ * 2);
  bf16*  ws_q    = (bf16*) alloc((size_t)B_ * H_ * S_ * D_ * 2);
  bf16*  ws_k    = (bf16*) alloc((size_t)B_ * H_ * S_ * D_ * 2);
  float* ws_vw   = (float*)alloc((size_t)3 * B_ * H_ * S_ * 4);
  bf16*  ws_Wt   = (bf16*) alloc((size_t)NTOT * E_ * 2);
  float* ws_bias = (float*)alloc((size_t)NTOT * 4);

  hipMemsetAsync(d_out, 0, (size_t)B_ * S_ * 3 * 4, stream);

  int n4 = B_ * S_ * E_ / 4;
  cast_feats<<<(n4 + 255) / 256, 256, 0, stream>>>(feats, ws_fb, n4);

  transpose_w<<<dim3(12, 12, 2), 256, 0, stream>>>(Wq, Wk, ws_Wt);

  int prep_n = 96 * E_ + NTOT;
  prep_vwx<<<(prep_n + 255) / 256, 256, 0, stream>>>(
      Wv, bv, bq, bk, Wfx, Wfy, Wfz, ws_Wt, ws_bias);

  gemm_qkv<<<dim3(NTOT / 128, B_ * S_ / 128), 256, 0, stream>>>(
      ws_fb, ws_Wt, ws_bias, ws_q, ws_k, ws_vw);

  attn_kernel<<<B_ * H_, 256, 0, stream>>>(ws_q, ws_k, ws_vw, attn_bias,
                                           delta_pos, (float*)d_out);
}